// Round 27
// baseline (250.283 us; speedup 1.0000x reference)
//
#include <hip/hip_runtime.h>
#include <hip/hip_bf16.h>

#define AS1 __attribute__((address_space(1)))
#define AS3 __attribute__((address_space(3)))

typedef __hip_bfloat16 bf16;
typedef short bf16x8 __attribute__((ext_vector_type(8)));
typedef float f32x4 __attribute__((ext_vector_type(4)));

static constexpr int D = 1024, S = 2048, NB = 4, NH = 16, DK = 64;
static constexpr int M = NB * S;  // 8192

__device__ __forceinline__ void gload16(void* lds_dst, const void* gsrc) {
  __builtin_amdgcn_global_load_lds((const AS1 void*)gsrc, (AS3 void*)lds_dst, 16, 0, 0);
}

// ---------------- fp32 -> bf16 convert (x) ----------------
__global__ void cvt_bf16_kernel(const float* __restrict__ src, bf16* __restrict__ dst, int n) {
  int i = (blockIdx.x * blockDim.x + threadIdx.x) * 4;
  int stride = gridDim.x * blockDim.x * 4;
  for (; i < n; i += stride) {
    float4 v = *(const float4*)(src + i);
    union { bf16 h[4]; uint2 u; } t;
    t.h[0] = __float2bfloat16(v.x);
    t.h[1] = __float2bfloat16(v.y);
    t.h[2] = __float2bfloat16(v.z);
    t.h[3] = __float2bfloat16(v.w);
    *(uint2*)(dst + i) = t.u;
  }
}

// ---------------- fused fp32 -> bf16 convert for the 4 weights ----------------
__global__ void cvt_w4_kernel(const float* __restrict__ s0, const float* __restrict__ s1,
                              const float* __restrict__ s2, const float* __restrict__ s3,
                              bf16* __restrict__ d0, bf16* __restrict__ d1,
                              bf16* __restrict__ d2, bf16* __restrict__ d3) {
  const float* src;
  bf16* dst;
  if (blockIdx.y == 0)      { src = s0; dst = d0; }
  else if (blockIdx.y == 1) { src = s1; dst = d1; }
  else if (blockIdx.y == 2) { src = s2; dst = d2; }
  else                      { src = s3; dst = d3; }
  const int n = D * D;
  int i = (blockIdx.x * blockDim.x + threadIdx.x) * 4;
  int stride = gridDim.x * blockDim.x * 4;
  for (; i < n; i += stride) {
    float4 v = *(const float4*)(src + i);
    union { bf16 h[4]; uint2 u; } t;
    t.h[0] = __float2bfloat16(v.x);
    t.h[1] = __float2bfloat16(v.y);
    t.h[2] = __float2bfloat16(v.z);
    t.h[3] = __float2bfloat16(v.w);
    *(uint2*)(dst + i) = t.u;
  }
}

// ---------------- NT GEMM: C[m,n] = sum_k A[m,k]*Bw[n,k] ----------------
// MODE 0: write bf16 to [B,H,S,64] layout (proj for Q/K), scaled
// MODE 1: write bf16 to Vt [B,H,64,S] layout (A=Wv, B=x)
// MODE 2: write fp32 row-major [M,N] (final output projection)
template <int MODE>
__global__ __launch_bounds__(256)
void gemm_bt(const bf16* __restrict__ A, const bf16* __restrict__ Bw,
             void* __restrict__ out, int K, int ldc, float scale) {
  __shared__ __align__(16) char lds[32768];
  char* Asm = lds;
  char* Bsm = lds + 16384;
  const int tid = threadIdx.x;
  const int w = tid >> 6, l = tid & 63;
  const int ql = l & 15, g = l >> 4;
  const int rowA = blockIdx.x * 128;
  const int rowB = blockIdx.y * 128;
  const int wr = (w >> 1) * 64, wc = (w & 1) * 64;

  f32x4 acc[4][4] = {};

  for (int k0 = 0; k0 < K; k0 += 64) {
#pragma unroll
    for (int i = 0; i < 4; ++i) {
      int o = ((i * 4 + w) << 10) + (l << 4);
      int row = o >> 7;
      int u = ((o >> 4) & 7) ^ (row & 7);
      gload16(Asm + ((i * 4 + w) << 10), A + (size_t)(rowA + row) * K + k0 + (u << 3));
      gload16(Bsm + ((i * 4 + w) << 10), Bw + (size_t)(rowB + row) * K + k0 + (u << 3));
    }
    __syncthreads();
#pragma unroll
    for (int kk = 0; kk < 2; ++kk) {
      bf16x8 af[4], bfr[4];
#pragma unroll
      for (int m = 0; m < 4; ++m) {
        int row = wr + m * 16 + ql;
        int sub = ((kk << 2) + g) ^ (row & 7);
        af[m] = *(const bf16x8*)(Asm + row * 128 + sub * 16);
      }
#pragma unroll
      for (int n = 0; n < 4; ++n) {
        int row = wc + n * 16 + ql;
        int sub = ((kk << 2) + g) ^ (row & 7);
        bfr[n] = *(const bf16x8*)(Bsm + row * 128 + sub * 16);
      }
#pragma unroll
      for (int m = 0; m < 4; ++m)
#pragma unroll
        for (int n = 0; n < 4; ++n)
          acc[m][n] = __builtin_amdgcn_mfma_f32_16x16x32_bf16(af[m], bfr[n], acc[m][n], 0, 0, 0);
    }
    __syncthreads();
  }

#pragma unroll
  for (int m = 0; m < 4; ++m)
#pragma unroll
    for (int n = 0; n < 4; ++n)
#pragma unroll
      for (int r = 0; r < 4; ++r) {
        int gm = rowA + wr + m * 16 + g * 4 + r;
        int gn = rowB + wc + n * 16 + ql;
        float v = acc[m][n][r] * scale;
        if (MODE == 0) {
          int b = gm >> 11, s = gm & 2047, h = gn >> 6, d = gn & 63;
          ((bf16*)out)[(((size_t)(b * 16 + h) * S) + s) * DK + d] = __float2bfloat16(v);
        } else if (MODE == 1) {
          int b = gn >> 11, s = gn & 2047;
          ((bf16*)out)[((size_t)b * 1024 + gm) * S + s] = __float2bfloat16(v);
        } else {
          ((float*)out)[(size_t)gm * ldc + gn] = v;
        }
      }
}

// ---------------- causal flash attention (v13 = v7 with KVBLK=128) ----------------
// 512 blocks x 4 waves. id: head bh=(id&7)+8*(id>>6) (8 blocks/head, XCD-local),
// x=(id>>3)&7. Wave w owns pair p = x + 8w, strips {p, 63-p} sequentially.
// KVBLK=128: T_j = (j+4)>>2 and T_p + T_{63-p} = 17 for ALL p -> balance kept.
// Fewer, fatter tiles: halved per-tile overhead, deeper load batching; VGPR
// (~210) is free at grid-limited 2 waves/SIMD. Same P-swizzle (row stride 256B).
// Q pre-scaled by 1/8. Q,K: [B,H,S,64]; Vt: [B,H,64,S]; O: [B,S,H*64]
__global__ __launch_bounds__(256)
void attn_kernel(const bf16* __restrict__ Q, const bf16* __restrict__ Km,
                 const bf16* __restrict__ Vt, bf16* __restrict__ O) {
  __shared__ __align__(16) char P[4][2][4096];   // per-wave per-sub [16q][128kv] bf16, swizzled
  const int tid = threadIdx.x;
  const int w = tid >> 6, l = tid & 63;
  const int ql = l & 15, g = l >> 4;
  const int id = blockIdx.x;
  const int bh = (id & 7) + 8 * (id >> 6);   // XCD-local head
  const int x = (id >> 3) & 7;
  const int p = x + 8 * w;                   // pair index 0..31
  const int swz = (ql & 7) << 4;
  const float L2E = 1.44269504f;
  const float THR = 8.0f;

  const bf16* Qb = Q + (size_t)bh * S * DK;
  const bf16* Kb = Km + (size_t)bh * S * DK;
  const bf16* Vb = Vt + (size_t)bh * DK * S;
  const int bo = bh >> 4, hh = bh & 15;
  bf16* Ob = O + (size_t)bo * S * D + hh * 64;

  for (int round = 0; round < 2; ++round) {
    const int j = round ? 63 - p : p;               // strip 0..63
    const int qbase = j << 5;                       // 32 q-rows
    const int kv_end = qbase + 32;

    bf16x8 qf[2][2];
#pragma unroll
    for (int sub = 0; sub < 2; ++sub)
#pragma unroll
      for (int kk = 0; kk < 2; ++kk)
        qf[sub][kk] = *(const bf16x8*)(Qb + (size_t)(qbase + sub * 16 + ql) * DK + kk * 32 + g * 8);

    f32x4 oacc[2][4] = {};
    float mrow[2] = {-3e38f, -3e38f};
    float lrow[2] = {0.f, 0.f};

    for (int kv0 = 0; kv0 < kv_end; kv0 += 128) {
      const bool last = (kv0 + 128 >= kv_end);

      // ---- QK^T over a 128-kv tile ----
      f32x4 st[2][8];
#pragma unroll
      for (int sub = 0; sub < 2; ++sub)
#pragma unroll
        for (int mt = 0; mt < 8; ++mt) st[sub][mt] = f32x4{0.f, 0.f, 0.f, 0.f};
      __builtin_amdgcn_s_setprio(1);
#pragma unroll
      for (int kk = 0; kk < 2; ++kk) {
        bf16x8 kf[8];
#pragma unroll
        for (int mt = 0; mt < 8; ++mt)
          kf[mt] = *(const bf16x8*)(Kb + (size_t)(kv0 + mt * 16 + ql) * DK + kk * 32 + g * 8);
#pragma unroll
        for (int sub = 0; sub < 2; ++sub)
#pragma unroll
          for (int mt = 0; mt < 8; ++mt)
            st[sub][mt] = __builtin_amdgcn_mfma_f32_16x16x32_bf16(kf[mt], qf[sub][kk], st[sub][mt], 0, 0, 0);
      }
      __builtin_amdgcn_s_setprio(0);

      // ---- hoist V loads (latency hides under softmax) ----
      bf16x8 vf[4][4];
#pragma unroll
      for (int kk = 0; kk < 4; ++kk)
#pragma unroll
        for (int n = 0; n < 4; ++n)
          vf[kk][n] = *(const bf16x8*)(Vb + (size_t)(n * 16 + ql) * S + kv0 + kk * 32 + g * 8);

      // ---- softmax (defer-max, lane-local common path) ----
#pragma unroll
      for (int sub = 0; sub < 2; ++sub) {
        const int qpos = qbase + sub * 16 + ql;
        if (last) {
#pragma unroll
          for (int mt = 0; mt < 8; ++mt)
#pragma unroll
            for (int r = 0; r < 4; ++r) {
              int kvpos = kv0 + mt * 16 + g * 4 + r;
              if (kvpos > qpos) st[sub][mt][r] = -3e38f;
            }
        }
        float tmax = st[sub][0][0];
#pragma unroll
        for (int mt = 0; mt < 8; ++mt)
#pragma unroll
          for (int r = 0; r < 4; ++r) tmax = fmaxf(tmax, st[sub][mt][r]);
        if (__any(tmax > mrow[sub] + THR)) {
          float rm = tmax;
          rm = fmaxf(rm, __shfl_xor(rm, 16, 64));
          rm = fmaxf(rm, __shfl_xor(rm, 32, 64));
          float mnew = fmaxf(mrow[sub], rm);
          float sc = exp2f((mrow[sub] - mnew) * L2E);
          mrow[sub] = mnew;
          lrow[sub] *= sc;
#pragma unroll
          for (int r = 0; r < 4; ++r) {            // acc rows are q = g*4+r
            float scr = __shfl(sc, g * 4 + r, 16);
#pragma unroll
            for (int n = 0; n < 4; ++n) oacc[sub][n][r] *= scr;
          }
        }
        float psum = 0.f;
#pragma unroll
        for (int mt = 0; mt < 8; ++mt) {
          union { ushort us[4]; uint2 u; } pk;
#pragma unroll
          for (int r = 0; r < 4; ++r) {
            float pv = exp2f((st[sub][mt][r] - mrow[sub]) * L2E);  // bounded by e^THR
            psum += pv;
            union { bf16 b; ushort u; } cv;
            cv.b = __float2bfloat16(pv);
            pk.us[r] = cv.u;
          }
          *(uint2*)&P[w][sub][((ql << 8) + (mt << 5) + (g << 3)) ^ swz] = pk.u;
        }
        lrow[sub] += psum;   // per-lane partial; reduced once in epilogue
      }

      // ---- PV over the 128-kv tile ----
      __builtin_amdgcn_s_setprio(1);
#pragma unroll
      for (int kk = 0; kk < 4; ++kk)
#pragma unroll
        for (int sub = 0; sub < 2; ++sub) {
          bf16x8 pa = *(const bf16x8*)&P[w][sub][((ql << 8) + (kk << 6) + (g << 4)) ^ swz];
#pragma unroll
          for (int n = 0; n < 4; ++n)
            oacc[sub][n] = __builtin_amdgcn_mfma_f32_16x16x32_bf16(pa, vf[kk][n], oacc[sub][n], 0, 0, 0);
        }
      __builtin_amdgcn_s_setprio(0);
    }

    // ---- epilogue for this strip ----
#pragma unroll
    for (int sub = 0; sub < 2; ++sub) {
      float lr = lrow[sub];
      lr += __shfl_xor(lr, 16, 64);
      lr += __shfl_xor(lr, 32, 64);
      float ldv[4];
#pragma unroll
      for (int r = 0; r < 4; ++r) ldv[r] = __shfl(lr, g * 4 + r, 16);
#pragma unroll
      for (int r = 0; r < 4; ++r) {
        int qrow = qbase + sub * 16 + g * 4 + r;
        float inv = 1.f / ldv[r];
#pragma unroll
        for (int n = 0; n < 4; ++n)
          Ob[(size_t)qrow * D + n * 16 + ql] = __float2bfloat16(oacc[sub][n][r] * inv);
      }
    }
  }
}

extern "C" void kernel_launch(void* const* d_in, const int* in_sizes, int n_in,
                              void* d_out, int out_size, void* d_ws, size_t ws_size,
                              hipStream_t stream) {
  const float* x  = (const float*)d_in[0];
  const float* wq = (const float*)d_in[1];
  const float* wk = (const float*)d_in[2];
  const float* wv = (const float*)d_in[3];
  const float* wo = (const float*)d_in[4];

  char* ws = (char*)d_ws;
  bf16* xb  = (bf16*)(ws);                      // 16 MB  [8192,1024]
  bf16* wqb = (bf16*)(ws + (16u << 20));        // 2 MB
  bf16* wkb = (bf16*)(ws + (18u << 20));
  bf16* wvb = (bf16*)(ws + (20u << 20));
  bf16* wob = (bf16*)(ws + (22u << 20));
  bf16* Qb  = (bf16*)(ws + (24u << 20));        // 16 MB [B,H,S,64] (pre-scaled 1/8)
  bf16* Kb  = (bf16*)(ws + (40u << 20));        // 16 MB [B,H,S,64]
  bf16* Vtb = (bf16*)(ws + (56u << 20));        // 16 MB [B,H,64,S]
  bf16* Ob  = (bf16*)(ws + (72u << 20));        // 16 MB [8192,1024]

  cvt_bf16_kernel<<<2048, 256, 0, stream>>>(x, xb, M * D);
  cvt_w4_kernel<<<dim3(256, 4), 256, 0, stream>>>(wq, wk, wv, wo, wqb, wkb, wvb, wob);

  // Q = x Wq^T (scaled 1/8), K = x Wk^T  -> [B,H,S,64]
  gemm_bt<0><<<dim3(M / 128, D / 128), 256, 0, stream>>>(xb, wqb, Qb, D, D, 0.125f);
  gemm_bt<0><<<dim3(M / 128, D / 128), 256, 0, stream>>>(xb, wkb, Kb, D, D, 1.0f);
  // Vt = Wv x^T -> [B,H,64,S]
  gemm_bt<1><<<dim3(D / 128, M / 128), 256, 0, stream>>>(wvb, xb, Vtb, D, D, 1.0f);

  attn_kernel<<<dim3(512), 256, 0, stream>>>(Qb, Kb, Vtb, Ob);

  // out = O Wo^T (fp32)
  gemm_bt<2><<<dim3(M / 128, D / 128), 256, 0, stream>>>(Ob, wob, d_out, D, D, 1.0f);
}

// Round 28
// 233.212 us; speedup vs baseline: 1.0732x; 1.0732x over previous
//
#include <hip/hip_runtime.h>
#include <hip/hip_bf16.h>

#define AS1 __attribute__((address_space(1)))
#define AS3 __attribute__((address_space(3)))

typedef __hip_bfloat16 bf16;
typedef short bf16x8 __attribute__((ext_vector_type(8)));
typedef float f32x4 __attribute__((ext_vector_type(4)));

static constexpr int D = 1024, S = 2048, NB = 4, NH = 16, DK = 64;
static constexpr int M = NB * S;  // 8192

__device__ __forceinline__ void gload16(void* lds_dst, const void* gsrc) {
  __builtin_amdgcn_global_load_lds((const AS1 void*)gsrc, (AS3 void*)lds_dst, 16, 0, 0);
}

// ---------------- fp32 -> bf16 convert (x) ----------------
__global__ void cvt_bf16_kernel(const float* __restrict__ src, bf16* __restrict__ dst, int n) {
  int i = (blockIdx.x * blockDim.x + threadIdx.x) * 4;
  int stride = gridDim.x * blockDim.x * 4;
  for (; i < n; i += stride) {
    float4 v = *(const float4*)(src + i);
    union { bf16 h[4]; uint2 u; } t;
    t.h[0] = __float2bfloat16(v.x);
    t.h[1] = __float2bfloat16(v.y);
    t.h[2] = __float2bfloat16(v.z);
    t.h[3] = __float2bfloat16(v.w);
    *(uint2*)(dst + i) = t.u;
  }
}

// ---------------- fused fp32 -> bf16 convert for the 4 weights ----------------
__global__ void cvt_w4_kernel(const float* __restrict__ s0, const float* __restrict__ s1,
                              const float* __restrict__ s2, const float* __restrict__ s3,
                              bf16* __restrict__ d0, bf16* __restrict__ d1,
                              bf16* __restrict__ d2, bf16* __restrict__ d3) {
  const float* src;
  bf16* dst;
  if (blockIdx.y == 0)      { src = s0; dst = d0; }
  else if (blockIdx.y == 1) { src = s1; dst = d1; }
  else if (blockIdx.y == 2) { src = s2; dst = d2; }
  else                      { src = s3; dst = d3; }
  const int n = D * D;
  int i = (blockIdx.x * blockDim.x + threadIdx.x) * 4;
  int stride = gridDim.x * blockDim.x * 4;
  for (; i < n; i += stride) {
    float4 v = *(const float4*)(src + i);
    union { bf16 h[4]; uint2 u; } t;
    t.h[0] = __float2bfloat16(v.x);
    t.h[1] = __float2bfloat16(v.y);
    t.h[2] = __float2bfloat16(v.z);
    t.h[3] = __float2bfloat16(v.w);
    *(uint2*)(dst + i) = t.u;
  }
}

// ---------------- NT GEMM: C[m,n] = sum_k A[m,k]*Bw[n,k] ----------------
// MODE 0: write bf16 to [B,H,S,64] layout (proj for Q/K), scaled
// MODE 1: write bf16 to Vt [B,H,64,S] layout (A=Wv, B=x)
// MODE 2: write fp32 row-major [M,N] (final output projection)
template <int MODE>
__global__ __launch_bounds__(256)
void gemm_bt(const bf16* __restrict__ A, const bf16* __restrict__ Bw,
             void* __restrict__ out, int K, int ldc, float scale) {
  __shared__ __align__(16) char lds[32768];
  char* Asm = lds;
  char* Bsm = lds + 16384;
  const int tid = threadIdx.x;
  const int w = tid >> 6, l = tid & 63;
  const int ql = l & 15, g = l >> 4;
  const int rowA = blockIdx.x * 128;
  const int rowB = blockIdx.y * 128;
  const int wr = (w >> 1) * 64, wc = (w & 1) * 64;

  f32x4 acc[4][4] = {};

  for (int k0 = 0; k0 < K; k0 += 64) {
#pragma unroll
    for (int i = 0; i < 4; ++i) {
      int o = ((i * 4 + w) << 10) + (l << 4);
      int row = o >> 7;
      int u = ((o >> 4) & 7) ^ (row & 7);
      gload16(Asm + ((i * 4 + w) << 10), A + (size_t)(rowA + row) * K + k0 + (u << 3));
      gload16(Bsm + ((i * 4 + w) << 10), Bw + (size_t)(rowB + row) * K + k0 + (u << 3));
    }
    __syncthreads();
#pragma unroll
    for (int kk = 0; kk < 2; ++kk) {
      bf16x8 af[4], bfr[4];
#pragma unroll
      for (int m = 0; m < 4; ++m) {
        int row = wr + m * 16 + ql;
        int sub = ((kk << 2) + g) ^ (row & 7);
        af[m] = *(const bf16x8*)(Asm + row * 128 + sub * 16);
      }
#pragma unroll
      for (int n = 0; n < 4; ++n) {
        int row = wc + n * 16 + ql;
        int sub = ((kk << 2) + g) ^ (row & 7);
        bfr[n] = *(const bf16x8*)(Bsm + row * 128 + sub * 16);
      }
#pragma unroll
      for (int m = 0; m < 4; ++m)
#pragma unroll
        for (int n = 0; n < 4; ++n)
          acc[m][n] = __builtin_amdgcn_mfma_f32_16x16x32_bf16(af[m], bfr[n], acc[m][n], 0, 0, 0);
    }
    __syncthreads();
  }

#pragma unroll
  for (int m = 0; m < 4; ++m)
#pragma unroll
    for (int n = 0; n < 4; ++n)
#pragma unroll
      for (int r = 0; r < 4; ++r) {
        int gm = rowA + wr + m * 16 + g * 4 + r;
        int gn = rowB + wc + n * 16 + ql;
        float v = acc[m][n][r] * scale;
        if (MODE == 0) {
          int b = gm >> 11, s = gm & 2047, h = gn >> 6, d = gn & 63;
          ((bf16*)out)[(((size_t)(b * 16 + h) * S) + s) * DK + d] = __float2bfloat16(v);
        } else if (MODE == 1) {
          int b = gn >> 11, s = gn & 2047;
          ((bf16*)out)[((size_t)b * 1024 + gm) * S + s] = __float2bfloat16(v);
        } else {
          ((float*)out)[(size_t)gm * ldc + gn] = v;
        }
      }
}

// ---------------- causal flash attention (v7: complementary pairs in-wave) ----------------
// 512 blocks x 4 waves. id: head bh=(id&7)+8*(id>>6) (8 blocks/head, XCD-local),
// x=(id>>3)&7. Per head: 64 strips of 32 q-rows = 32 complementary pairs.
// Wave w owns pair p = x + 8w and processes strips {p, 63-p} sequentially
// -> exactly 65 kv-tiles for EVERY wave (perfect balance, no sync, no merge).
// KVBLK=64, per-sub P tiles, defer-max, V-hoist, setprio. Q pre-scaled by 1/8.
// Q,K: [B,H,S,64]; Vt: [B,H,64,S]; O: [B,S,H*64]
__global__ __launch_bounds__(256)
void attn_kernel(const bf16* __restrict__ Q, const bf16* __restrict__ Km,
                 const bf16* __restrict__ Vt, bf16* __restrict__ O) {
  __shared__ __align__(16) char P[4][2][2048];   // per-wave per-sub [16q][64kv] bf16, swizzled
  const int tid = threadIdx.x;
  const int w = tid >> 6, l = tid & 63;
  const int ql = l & 15, g = l >> 4;
  const int id = blockIdx.x;
  const int bh = (id & 7) + 8 * (id >> 6);   // XCD-local head
  const int x = (id >> 3) & 7;
  const int p = x + 8 * w;                   // pair index 0..31
  const int swz = (ql & 7) << 4;
  const float L2E = 1.44269504f;
  const float THR = 8.0f;

  const bf16* Qb = Q + (size_t)bh * S * DK;
  const bf16* Kb = Km + (size_t)bh * S * DK;
  const bf16* Vb = Vt + (size_t)bh * DK * S;
  const int bo = bh >> 4, hh = bh & 15;
  bf16* Ob = O + (size_t)bo * S * D + hh * 64;

  for (int round = 0; round < 2; ++round) {
    const int j = round ? 63 - p : p;               // strip 0..63
    const int qbase = j << 5;                       // 32 q-rows
    const int kv_end = qbase + 32;

    bf16x8 qf[2][2];
#pragma unroll
    for (int sub = 0; sub < 2; ++sub)
#pragma unroll
      for (int kk = 0; kk < 2; ++kk)
        qf[sub][kk] = *(const bf16x8*)(Qb + (size_t)(qbase + sub * 16 + ql) * DK + kk * 32 + g * 8);

    f32x4 oacc[2][4] = {};
    float mrow[2] = {-3e38f, -3e38f};
    float lrow[2] = {0.f, 0.f};

    for (int kv0 = 0; kv0 < kv_end; kv0 += 64) {
      const bool last = (kv0 + 64 >= kv_end);

      // ---- QK^T ----
      f32x4 st[2][4];
#pragma unroll
      for (int sub = 0; sub < 2; ++sub)
#pragma unroll
        for (int mt = 0; mt < 4; ++mt) st[sub][mt] = f32x4{0.f, 0.f, 0.f, 0.f};
      __builtin_amdgcn_s_setprio(1);
#pragma unroll
      for (int kk = 0; kk < 2; ++kk) {
        bf16x8 kf[4];
#pragma unroll
        for (int mt = 0; mt < 4; ++mt)
          kf[mt] = *(const bf16x8*)(Kb + (size_t)(kv0 + mt * 16 + ql) * DK + kk * 32 + g * 8);
#pragma unroll
        for (int sub = 0; sub < 2; ++sub)
#pragma unroll
          for (int mt = 0; mt < 4; ++mt)
            st[sub][mt] = __builtin_amdgcn_mfma_f32_16x16x32_bf16(kf[mt], qf[sub][kk], st[sub][mt], 0, 0, 0);
      }
      __builtin_amdgcn_s_setprio(0);

      // ---- hoist V loads (latency hides under softmax) ----
      bf16x8 vf[2][4];
#pragma unroll
      for (int kk = 0; kk < 2; ++kk)
#pragma unroll
        for (int n = 0; n < 4; ++n)
          vf[kk][n] = *(const bf16x8*)(Vb + (size_t)(n * 16 + ql) * S + kv0 + kk * 32 + g * 8);

      // ---- softmax (defer-max, lane-local common path) ----
#pragma unroll
      for (int sub = 0; sub < 2; ++sub) {
        const int qpos = qbase + sub * 16 + ql;
        if (last) {
#pragma unroll
          for (int mt = 0; mt < 4; ++mt)
#pragma unroll
            for (int r = 0; r < 4; ++r) {
              int kvpos = kv0 + mt * 16 + g * 4 + r;
              if (kvpos > qpos) st[sub][mt][r] = -3e38f;
            }
        }
        float tmax = st[sub][0][0];
#pragma unroll
        for (int mt = 0; mt < 4; ++mt)
#pragma unroll
          for (int r = 0; r < 4; ++r) tmax = fmaxf(tmax, st[sub][mt][r]);
        if (__any(tmax > mrow[sub] + THR)) {
          float rm = tmax;
          rm = fmaxf(rm, __shfl_xor(rm, 16, 64));
          rm = fmaxf(rm, __shfl_xor(rm, 32, 64));
          float mnew = fmaxf(mrow[sub], rm);
          float sc = exp2f((mrow[sub] - mnew) * L2E);
          mrow[sub] = mnew;
          lrow[sub] *= sc;
#pragma unroll
          for (int r = 0; r < 4; ++r) {            // acc rows are q = g*4+r
            float scr = __shfl(sc, g * 4 + r, 16);
#pragma unroll
            for (int n = 0; n < 4; ++n) oacc[sub][n][r] *= scr;
          }
        }
        float psum = 0.f;
#pragma unroll
        for (int mt = 0; mt < 4; ++mt) {
          union { ushort us[4]; uint2 u; } pk;
#pragma unroll
          for (int r = 0; r < 4; ++r) {
            float pv = exp2f((st[sub][mt][r] - mrow[sub]) * L2E);  // bounded by e^THR
            psum += pv;
            union { bf16 b; ushort u; } cv;
            cv.b = __float2bfloat16(pv);
            pk.us[r] = cv.u;
          }
          *(uint2*)&P[w][sub][((ql << 7) + (mt << 5) + (g << 3)) ^ swz] = pk.u;
        }
        lrow[sub] += psum;   // per-lane partial; reduced once in epilogue
      }

      // ---- PV ----
      __builtin_amdgcn_s_setprio(1);
#pragma unroll
      for (int kk = 0; kk < 2; ++kk)
#pragma unroll
        for (int sub = 0; sub < 2; ++sub) {
          bf16x8 pa = *(const bf16x8*)&P[w][sub][((ql << 7) + (kk << 6) + (g << 4)) ^ swz];
#pragma unroll
          for (int n = 0; n < 4; ++n)
            oacc[sub][n] = __builtin_amdgcn_mfma_f32_16x16x32_bf16(pa, vf[kk][n], oacc[sub][n], 0, 0, 0);
        }
      __builtin_amdgcn_s_setprio(0);
    }

    // ---- epilogue for this strip ----
#pragma unroll
    for (int sub = 0; sub < 2; ++sub) {
      float lr = lrow[sub];
      lr += __shfl_xor(lr, 16, 64);
      lr += __shfl_xor(lr, 32, 64);
      float ldv[4];
#pragma unroll
      for (int r = 0; r < 4; ++r) ldv[r] = __shfl(lr, g * 4 + r, 16);
#pragma unroll
      for (int r = 0; r < 4; ++r) {
        int qrow = qbase + sub * 16 + g * 4 + r;
        float inv = 1.f / ldv[r];
#pragma unroll
        for (int n = 0; n < 4; ++n)
          Ob[(size_t)qrow * D + n * 16 + ql] = __float2bfloat16(oacc[sub][n][r] * inv);
      }
    }
  }
}

extern "C" void kernel_launch(void* const* d_in, const int* in_sizes, int n_in,
                              void* d_out, int out_size, void* d_ws, size_t ws_size,
                              hipStream_t stream) {
  const float* x  = (const float*)d_in[0];
  const float* wq = (const float*)d_in[1];
  const float* wk = (const float*)d_in[2];
  const float* wv = (const float*)d_in[3];
  const float* wo = (const float*)d_in[4];

  char* ws = (char*)d_ws;
  bf16* xb  = (bf16*)(ws);                      // 16 MB  [8192,1024]
  bf16* wqb = (bf16*)(ws + (16u << 20));        // 2 MB
  bf16* wkb = (bf16*)(ws + (18u << 20));
  bf16* wvb = (bf16*)(ws + (20u << 20));
  bf16* wob = (bf16*)(ws + (22u << 20));
  bf16* Qb  = (bf16*)(ws + (24u << 20));        // 16 MB [B,H,S,64] (pre-scaled 1/8)
  bf16* Kb  = (bf16*)(ws + (40u << 20));        // 16 MB [B,H,S,64]
  bf16* Vtb = (bf16*)(ws + (56u << 20));        // 16 MB [B,H,64,S]
  bf16* Ob  = (bf16*)(ws + (72u << 20));        // 16 MB [8192,1024]

  cvt_bf16_kernel<<<2048, 256, 0, stream>>>(x, xb, M * D);
  cvt_w4_kernel<<<dim3(256, 4), 256, 0, stream>>>(wq, wk, wv, wo, wqb, wkb, wvb, wob);

  // Q = x Wq^T (scaled 1/8), K = x Wk^T  -> [B,H,S,64]
  gemm_bt<0><<<dim3(M / 128, D / 128), 256, 0, stream>>>(xb, wqb, Qb, D, D, 0.125f);
  gemm_bt<0><<<dim3(M / 128, D / 128), 256, 0, stream>>>(xb, wkb, Kb, D, D, 1.0f);
  // Vt = Wv x^T -> [B,H,64,S]
  gemm_bt<1><<<dim3(D / 128, M / 128), 256, 0, stream>>>(wvb, xb, Vtb, D, D, 1.0f);

  attn_kernel<<<dim3(512), 256, 0, stream>>>(Qb, Kb, Vtb, Ob);

  // out = O Wo^T (fp32)
  gemm_bt<2><<<dim3(M / 128, D / 128), 256, 0, stream>>>(Ob, wob, d_out, D, D, 1.0f);
}